// Round 3
// baseline (84.506 us; speedup 1.0000x reference)
//
#include <hip/hip_runtime.h>
#include <math.h>

#define HDIM  512
#define NH    32
#define LLEN  8192
#define BLOCK 256

// One block per h. Thread tid owns 32 consecutive l: [32*tid, 32*tid+32).
// Base T(32*tid) from two-level LDS table (fp64-built): 32*tid = 512*hi + 32*lo.
// Chains: 4 float2 pairs (offset o, o+16), o in [0,4), advanced by W4 over 4 j-steps.
__global__ __launch_bounds__(BLOCK) void s4d_kernel(
    const float* __restrict__ C,          // (H, NH, 2)
    const float* __restrict__ log_dt,     // (H,)
    const float* __restrict__ log_A_real, // (H, NH)
    const float* __restrict__ A_imag,     // (H, NH)
    float* __restrict__ out)              // (H, LLEN)
{
    __shared__ float2 tabA[NH + 1][16];   // exp(dtA * 32*lo)
    __shared__ float2 tabB[NH + 1][16];   // exp(dtA * 512*hi)
    __shared__ float4 s_c0[NH + 1];       // {2*Cs.re, 2*Cs.im, w1.re, w1.im}
    __shared__ float4 s_c1[NH + 1];       // {W4.re, W4.im, W16.re, W16.im}

    const int h   = blockIdx.x;
    const int tid = threadIdx.x;

    // ---------- prep: build tables + per-mode constants (fp64) ----------
    {
        const int n = tid & 31;
        const int g = tid >> 5;                 // 0..7: g<4 -> A entries, g>=4 -> B
        const double dt  = exp((double)log_dt[h]);
        const double Are = -exp((double)log_A_real[h * NH + n]);
        const double Aim = (double)A_imag[h * NH + n];
        const double dre = Are * dt, dim = Aim * dt;

        const bool   isB   = (g >= 4);
        const double scale = isB ? 512.0 : 32.0;
        const int    i0    = (isB ? (g - 4) : g) * 4;

        // first entry exp(dtA*scale*i0), then fp64 recurrence by exp(dtA*scale)
        double s0, c0d; sincos(dim * scale * (double)i0, &s0, &c0d);
        const double m0 = exp(dre * scale * (double)i0);
        double er = m0 * c0d, ei = m0 * s0;
        double ss, cs; sincos(dim * scale, &ss, &cs);
        const double ms = exp(dre * scale);
        const double str = ms * cs, sti = ms * ss;

        float2* dst = isB ? &tabB[n][0] : &tabA[n][0];
        for (int k = 0; k < 4; ++k) {
            dst[i0 + k] = make_float2((float)er, (float)ei);
            const double t = er * str - ei * sti;
            ei = er * sti + ei * str;
            er = t;
        }

        if (g == 0) {   // per-mode constants, n = tid in [0,32)
            double s1, c1; sincos(dim, &s1, &c1);
            const double em  = exp(dre);
            const double w1r = em * c1, w1i = em * s1;
            // C_scaled = Cc*(exp(dtA)-1)/A ; store 2*C_scaled
            const double nre = w1r - 1.0, nim = w1i;
            const double den = Are * Are + Aim * Aim;
            const double fre = (nre * Are + nim * Aim) / den;
            const double fim = (nim * Are - nre * Aim) / den;
            const double Cre = (double)C[(h * NH + n) * 2 + 0];
            const double Cim = (double)C[(h * NH + n) * 2 + 1];
            s_c0[n] = make_float4((float)(2.0 * (Cre * fre - Cim * fim)),
                                  (float)(2.0 * (Cre * fim + Cim * fre)),
                                  (float)w1r, (float)w1i);
            double s4, c4;   sincos(dim * 4.0,  &s4,  &c4);
            double s16, c16; sincos(dim * 16.0, &s16, &c16);
            const double m4 = exp(dre * 4.0), m16 = exp(dre * 16.0);
            s_c1[n] = make_float4((float)(m4 * c4),  (float)(m4 * s4),
                                  (float)(m16 * c16), (float)(m16 * s16));
        }
    }
    __syncthreads();

    const int lo = tid & 15, hi = tid >> 4;

    float2 acc[4][4];
#pragma unroll
    for (int j = 0; j < 4; ++j)
#pragma unroll
        for (int o = 0; o < 4; ++o) acc[j][o] = make_float2(0.f, 0.f);

    float2 A2 = tabA[0][lo], B2 = tabB[0][hi];
    float4 k0 = s_c0[0],     k1 = s_c1[0];

#pragma unroll 1
    for (int n = 0; n < NH; ++n) {
        // prefetch next mode's table entries + constants (row NH is padding)
        const float2 pA = tabA[n + 1][lo], pB = tabB[n + 1][hi];
        const float4 p0 = s_c0[n + 1],     p1 = s_c1[n + 1];

        const float cr  = k0.x, ci  = k0.y, w1r = k0.z, w1i = k0.w;
        const float W4r = k1.x, W4i = k1.y, W16r = k1.z, W16i = k1.w;

        // base T(lbase) = A2*B2, then w1-chain for offsets 1..3
        float Tr[4], Ti[4];
        Tr[0] = fmaf(A2.x, B2.x, -(A2.y * B2.y));
        Ti[0] = fmaf(A2.x, B2.y,  (A2.y * B2.x));
#pragma unroll
        for (int o = 1; o < 4; ++o) {
            Tr[o] = fmaf(Tr[o-1], w1r, -(Ti[o-1] * w1i));
            Ti[o] = fmaf(Tr[o-1], w1i,  (Ti[o-1] * w1r));
        }
        // pair each offset with its +16 partner (multiply by W16)
        float2 Tr2[4], Ti2[4];
#pragma unroll
        for (int o = 0; o < 4; ++o) {
            const float ur = fmaf(Tr[o], W16r, -(Ti[o] * W16i));
            const float ui = fmaf(Tr[o], W16i,  (Ti[o] * W16r));
            Tr2[o] = make_float2(Tr[o], ur);
            Ti2[o] = make_float2(Ti[o], ui);
        }

#pragma unroll
        for (int j = 0; j < 4; ++j) {
#pragma unroll
            for (int o = 0; o < 4; ++o) {
                acc[j][o].x = fmaf(cr, Tr2[o].x, fmaf(-ci, Ti2[o].x, acc[j][o].x));
                acc[j][o].y = fmaf(cr, Tr2[o].y, fmaf(-ci, Ti2[o].y, acc[j][o].y));
            }
            if (j < 3) {
#pragma unroll
                for (int o = 0; o < 4; ++o) {
                    const float nrx = fmaf(Tr2[o].x, W4r, -(Ti2[o].x * W4i));
                    const float nry = fmaf(Tr2[o].y, W4r, -(Ti2[o].y * W4i));
                    const float nix = fmaf(Tr2[o].x, W4i,  (Ti2[o].x * W4r));
                    const float niy = fmaf(Tr2[o].y, W4i,  (Ti2[o].y * W4r));
                    Tr2[o] = make_float2(nrx, nry);
                    Ti2[o] = make_float2(nix, niy);
                }
            }
        }
        A2 = pA; B2 = pB; k0 = p0; k1 = p1;
    }

    // epilogue: acc[j][o].x -> l = 32*tid + 4j + o ; acc[j][o].y -> +16
    float* orow = out + (size_t)h * LLEN + 32 * tid;
#pragma unroll
    for (int j = 0; j < 4; ++j) {
        *(float4*)(orow + 4 * j) =
            make_float4(acc[j][0].x, acc[j][1].x, acc[j][2].x, acc[j][3].x);
        *(float4*)(orow + 16 + 4 * j) =
            make_float4(acc[j][0].y, acc[j][1].y, acc[j][2].y, acc[j][3].y);
    }
}

extern "C" void kernel_launch(void* const* d_in, const int* in_sizes, int n_in,
                              void* d_out, int out_size, void* d_ws, size_t ws_size,
                              hipStream_t stream) {
    const float* C          = (const float*)d_in[0];
    const float* log_dt     = (const float*)d_in[1];
    const float* log_A_real = (const float*)d_in[2];
    const float* A_imag     = (const float*)d_in[3];
    float* out = (float*)d_out;

    s4d_kernel<<<HDIM, BLOCK, 0, stream>>>(C, log_dt, log_A_real, A_imag, out);
}

// Round 4
// 80.975 us; speedup vs baseline: 1.0436x; 1.0436x over previous
//
#include <hip/hip_runtime.h>
#include <math.h>

#define HDIM   512
#define NH     32
#define LLEN   8192
#define BLOCK  256
#define LSPLIT 2
#define LPB    (LLEN / LSPLIT)   // 4096 l per block
#define LPT    16                // consecutive l per thread

// Grid (LSPLIT, HDIM). Thread tid owns l in [ls*LPB + 16*tid, +16).
// Key idea: y_l = Re(2*Cs*w^l) obeys y_{l+1} = p*y_l - q*y_{l-1},
// p = 2*Re(w), q = |w|^2  ->  2 VALU ops per (l,n) + 1 acc add.
// Seeds y(l0), y(l0+1) from fp64-built two-level LDS tables (restart
// every 16 steps bounds fp32 drift). Modes processed in pairs for ILP.
__global__ __launch_bounds__(BLOCK) void s4d_kernel(
    const float* __restrict__ C,          // (H, NH, 2)
    const float* __restrict__ log_dt,     // (H,)
    const float* __restrict__ log_A_real, // (H, NH)
    const float* __restrict__ A_imag,     // (H, NH)
    float* __restrict__ out)              // (H, LLEN)
{
    __shared__ float2 tabA[NH][16];  // exp(dtA * 16*lo)
    __shared__ float2 tabB[NH][16];  // exp(dtA * (LPB*ls + 256*hi))
    __shared__ float4 s_cw[NH];      // {2Cs.re, 2Cs.im, w1.re, w1.im}
    __shared__ float2 s_pq[NH];      // {p = 2*Re(w1), q = |w1|^2}

    const int h   = blockIdx.y;
    const int ls  = blockIdx.x;
    const int tid = threadIdx.x;

    // ---------------- prep (fp64): tables + per-mode constants ----------------
    {
        const int n = tid & 31;
        const int g = tid >> 5;                  // 0..3 -> tabA, 4..7 -> tabB
        const double dt  = exp((double)log_dt[h]);
        const double Are = -exp((double)log_A_real[h * NH + n]);
        const double Aim = (double)A_imag[h * NH + n];
        const double dre = Are * dt, dim = Aim * dt;

        const bool   isB  = (g >= 4);
        const int    i0   = (isB ? (g - 4) : g) * 4;
        const double step = isB ? 256.0 : 16.0;
        const double base = isB ? ((double)(LPB * ls) + 256.0 * (double)i0)
                                : (16.0 * (double)i0);

        double s0, c0; sincos(dim * base, &s0, &c0);
        const double m0 = exp(dre * base);
        double er = m0 * c0, ei = m0 * s0;
        double ss, cs; sincos(dim * step, &ss, &cs);
        const double ms = exp(dre * step);
        const double str = ms * cs, sti = ms * ss;

        float2* dst = isB ? &tabB[n][0] : &tabA[n][0];
        for (int k = 0; k < 4; ++k) {
            dst[i0 + k] = make_float2((float)er, (float)ei);
            const double t = er * str - ei * sti;
            ei = er * sti + ei * str;
            er = t;
        }

        if (g == 0) {                             // per-mode constants
            double s1, c1; sincos(dim, &s1, &c1);
            const double em  = exp(dre);
            const double w1r = em * c1, w1i = em * s1;
            const double nre = w1r - 1.0, nim = w1i;
            const double den = Are * Are + Aim * Aim;
            const double fre = (nre * Are + nim * Aim) / den;
            const double fim = (nim * Are - nre * Aim) / den;
            const double Cre = (double)C[(h * NH + n) * 2 + 0];
            const double Cim = (double)C[(h * NH + n) * 2 + 1];
            s_cw[n] = make_float4((float)(2.0 * (Cre * fre - Cim * fim)),
                                  (float)(2.0 * (Cre * fim + Cim * fre)),
                                  (float)w1r, (float)w1i);
            s_pq[n] = make_float2((float)(2.0 * w1r), (float)(em * em));
        }
    }
    __syncthreads();

    const int lo = tid & 15, hi = tid >> 4;       // 16*tid = 256*hi + 16*lo

    float acc[LPT];
#pragma unroll
    for (int l = 0; l < LPT; ++l) acc[l] = 0.0f;

#pragma unroll 1
    for (int n = 0; n < NH; n += 2) {
        const float2 Aa = tabA[n][lo],     Ba = tabB[n][hi];
        const float2 Ab = tabA[n + 1][lo], Bb = tabB[n + 1][hi];
        const float4 cwa = s_cw[n], cwb = s_cw[n + 1];
        const float2 pqa = s_pq[n], pqb = s_pq[n + 1];

        // T(l0) = A*B, seeds y(l0), y(l0+1)
        const float Tar = fmaf(Aa.x, Ba.x, -(Aa.y * Ba.y));
        const float Tai = fmaf(Aa.x, Ba.y,   Aa.y * Ba.x);
        const float Tbr = fmaf(Ab.x, Bb.x, -(Ab.y * Bb.y));
        const float Tbi = fmaf(Ab.x, Bb.y,   Ab.y * Bb.x);

        float ypa = fmaf(cwa.x, Tar, -(cwa.y * Tai));
        float ypb = fmaf(cwb.x, Tbr, -(cwb.y * Tbi));

        const float T1ar = fmaf(Tar, cwa.z, -(Tai * cwa.w));
        const float T1ai = fmaf(Tar, cwa.w,   Tai * cwa.z);
        const float T1br = fmaf(Tbr, cwb.z, -(Tbi * cwb.w));
        const float T1bi = fmaf(Tbr, cwb.w,   Tbi * cwb.z);

        float ya = fmaf(cwa.x, T1ar, -(cwa.y * T1ai));
        float yb = fmaf(cwb.x, T1br, -(cwb.y * T1bi));

        acc[0] += ypa + ypb;
        acc[1] += ya  + yb;

#pragma unroll
        for (int l = 2; l < LPT; ++l) {
            const float za = fmaf(pqa.x, ya, -(pqa.y * ypa));
            const float zb = fmaf(pqb.x, yb, -(pqb.y * ypb));
            acc[l] += za + zb;
            ypa = ya; ya = za;
            ypb = yb; yb = zb;
        }
    }

    float* orow = out + (size_t)h * LLEN + ls * LPB + LPT * tid;
#pragma unroll
    for (int j = 0; j < 4; ++j) {
        *(float4*)(orow + 4 * j) =
            make_float4(acc[4*j], acc[4*j+1], acc[4*j+2], acc[4*j+3]);
    }
}

extern "C" void kernel_launch(void* const* d_in, const int* in_sizes, int n_in,
                              void* d_out, int out_size, void* d_ws, size_t ws_size,
                              hipStream_t stream) {
    const float* C          = (const float*)d_in[0];
    const float* log_dt     = (const float*)d_in[1];
    const float* log_A_real = (const float*)d_in[2];
    const float* A_imag     = (const float*)d_in[3];
    float* out = (float*)d_out;

    dim3 grid(LSPLIT, HDIM);
    s4d_kernel<<<grid, BLOCK, 0, stream>>>(C, log_dt, log_A_real, A_imag, out);
}